// Round 5
// baseline (75.405 us; speedup 1.0000x reference)
//
#include <hip/hip_runtime.h>

// reference: out[b,s,:] = emb_weight[ clamp(lookup_table[input_ids[b,s]], 0, 31999) ]
// shapes: input_ids [16,4096] i32, lookup_table [128000] i32, emb_weight [32000,768] f32
// out [16,4096,768] f32
//
// R4 finding: 403MB (201 read + 201 write) @ 63us = 6.39 TB/s = mixed-copy
// ceiling. Zero gather reuse captured (reuse distance ~ L3 size). This round:
// 8 vocab-chunk passes to shrink read reuse distance -> ~103MB fewer HBM reads.

constexpr int EMB_DIM   = 768;            // floats per row
constexpr int ROW_F4    = EMB_DIM / 4;    // 192 float4 per row
constexpr int VOCAB     = 32000;
constexpr int NPASS     = 8;
constexpr int CHUNK     = VOCAB / NPASS;  // 4000 rows = 12.3 MB per chunk

typedef float vfloat4 __attribute__((ext_vector_type(4)));

__device__ __forceinline__ void store_nt_wa(vfloat4* p, vfloat4 v) {
    // write-around: keep the 201MB write stream from evicting the hot chunk
    asm volatile("global_store_dwordx4 %0, %1, off sc0 sc1 nt"
                 :: "v"(p), "v"(v) : "memory");
}

__global__ __launch_bounds__(256) void token_emb_gather(
    const int*     __restrict__ input_ids,
    const int*     __restrict__ lookup,
    const vfloat4* __restrict__ emb,   // [VOCAB][192]
    vfloat4*       __restrict__ out,   // [ntok][192]
    int nb_per_pass, int ntok)
{
    // grid = NPASS * nb_per_pass blocks, pass-major: blocks of pass p are
    // dispatched (mostly) before pass p+1 -> chunk p stays L3-resident.
    int pass  = blockIdx.x / nb_per_pass;
    int token = (blockIdx.x % nb_per_pass) * 4 + threadIdx.y;  // one wave per token
    if (token >= ntok) return;

    int id = lookup[input_ids[token]];          // wave-uniform -> broadcast
    id = min(max(id, 0), VOCAB - 1);            // clamp as in reference

    if (id / CHUNK != pass) return;             // wave-uniform branch, no divergence

    const vfloat4* __restrict__ src = emb + (size_t)id    * ROW_F4;
    vfloat4*       __restrict__ dst = out + (size_t)token * ROW_F4;

    int lane = threadIdx.x;                     // 0..63

    vfloat4 v0 = src[lane];
    vfloat4 v1 = src[lane + 64];
    vfloat4 v2 = src[lane + 128];
    store_nt_wa(dst + lane,       v0);
    store_nt_wa(dst + lane + 64,  v1);
    store_nt_wa(dst + lane + 128, v2);
}

extern "C" void kernel_launch(void* const* d_in, const int* in_sizes, int n_in,
                              void* d_out, int out_size, void* d_ws, size_t ws_size,
                              hipStream_t stream)
{
    const int*     input_ids = (const int*)d_in[0];
    const int*     lookup    = (const int*)d_in[1];
    const vfloat4* emb       = (const vfloat4*)d_in[2];
    vfloat4*       out       = (vfloat4*)d_out;

    int ntok = in_sizes[0];                     // 16*4096 = 65536
    int nb_per_pass = (ntok + 3) / 4;           // 16384

    dim3 block(64, 4);
    dim3 grid(nb_per_pass * NPASS);
    token_emb_gather<<<grid, block, 0, stream>>>(input_ids, lookup, emb, out,
                                                 nb_per_pass, ntok);
}